// Round 1
// baseline (776.090 us; speedup 1.0000x reference)
//
#include <hip/hip_runtime.h>
#include <stdint.h>

#define HIDDEN 512
#define ONEHOT 64
#define EDIM   576   // HIDDEN + ONEHOT
#define BATCH  128
#define LSEQ   1024
#define FANIN  1088  // 2*HIDDEN + ONEHOT

typedef __attribute__((ext_vector_type(8))) short short8;
typedef __attribute__((ext_vector_type(4))) float f32x4;

__device__ inline unsigned short f2bf(float x) {
    union { float f; unsigned int u; } v; v.f = x;
    unsigned int u = v.u;
    // round-to-nearest-even bf16 truncation (inputs are finite)
    unsigned int r = (u + 0x7FFFu + ((u >> 16) & 1u)) >> 16;
    return (unsigned short)r;
}

// ---------------- part_h[b][h] = hidden[b,:] . W[h,0:512] + bias[h] -------
__global__ __launch_bounds__(256) void k_parth(const float* __restrict__ hidden,
                                               const float* __restrict__ W,
                                               const float* __restrict__ bias,
                                               float* __restrict__ ph) {
    int gid = blockIdx.x * blockDim.x + threadIdx.x;   // 65536 threads
    int b = gid & (BATCH - 1);
    int h = gid >> 7;                                  // wave-uniform h
    const float* hrow = hidden + b * HIDDEN;
    const float* wrow = W + h * FANIN;
    float acc = 0.f;
#pragma unroll 4
    for (int d = 0; d < HIDDEN; d += 4) {
        float4 hv = *(const float4*)(hrow + d);
        float4 wv = *(const float4*)(wrow + d);
        acc += hv.x * wv.x + hv.y * wv.y + hv.z * wv.z + hv.w * wv.w;
    }
    ph[b * HIDDEN + h] = acc + bias[h];
}

// ---------------- We (fp32, W[:,512:]) -> bf16 chunked [18][512][32] -------
__global__ __launch_bounds__(256) void k_convW(const float* __restrict__ W,
                                               unsigned short* __restrict__ WeB) {
    int i = blockIdx.x * blockDim.x + threadIdx.x;     // 294912 elems
    int kk = i & 31;
    int h  = (i >> 5) & 511;
    int kc = i >> 14;
    WeB[i] = f2bf(W[h * FANIN + HIDDEN + kc * 32 + kk]);
}

// ---------------- main fused: scores[r] = sum_h v[h]*tanh(enc[r].We[h]+ph) -
#define BK   32
#define LROW 40    // BK + 8 pad, in ushorts -> 80B row stride (2-way banks, free)
#define MT   64    // rows per workgroup

__global__ __launch_bounds__(512, 2) void k_main(
        const float* __restrict__ enc,            // [L][B][EDIM]
        const unsigned short* __restrict__ WeB,   // [18][512][32] bf16
        const float* __restrict__ ph,             // [B][HIDDEN] (bias included)
        const float* __restrict__ v,
        float* __restrict__ scores)               // [L*B]
{
    __shared__ unsigned short aLds[MT * LROW];        //  5120 B
    __shared__ unsigned short bLds[HIDDEN * LROW];    // 40960 B
    __shared__ float sScore[MT];

    const int tid  = threadIdx.x;
    const int wave = tid >> 6;
    const int lane = tid & 63;
    const int c = lane & 15;      // column-in-16 (N index / A row index)
    const int q = lane >> 4;      // quad (k-octet select; C row group)

    const long rowBase = (long)blockIdx.x * MT;

    if (tid < MT) sScore[tid] = 0.f;

    f32x4 acc[4][4];
#pragma unroll
    for (int i = 0; i < 4; ++i)
#pragma unroll
        for (int j = 0; j < 4; ++j) acc[i][j] = (f32x4){0.f, 0.f, 0.f, 0.f};

    // A staging map: thread -> (row 0..63, 4-float group 0..7)
    const int arow = tid >> 3;
    const int acg  = tid & 7;
    const float* aptr = enc + (rowBase + arow) * EDIM + acg * 4;

    for (int kc = 0; kc < 18; ++kc) {
        // global loads first (let them fly before the barrier)
        float4 av = *(const float4*)(aptr + kc * BK);
        uint4 bv[4];
        const uint4* bsrc = (const uint4*)(WeB + kc * (HIDDEN * BK));
#pragma unroll
        for (int p = 0; p < 4; ++p) bv[p] = bsrc[p * 512 + tid];

        __syncthreads();   // previous iteration's LDS reads complete

        ushort4 aw;
        aw.x = f2bf(av.x); aw.y = f2bf(av.y); aw.z = f2bf(av.z); aw.w = f2bf(av.w);
        *(ushort4*)(&aLds[arow * LROW + acg * 4]) = aw;

#pragma unroll
        for (int p = 0; p < 4; ++p) {
            int o  = p * 8192 + tid * 16;   // byte offset in dense 32KB tile
            int hh = o >> 6;                // 64 B per h-row
            int kb = o & 63;
            *(uint4*)((char*)bLds + hh * (LROW * 2) + kb) = bv[p];
        }

        __syncthreads();

        short8 af[4], bfr[4];
#pragma unroll
        for (int am = 0; am < 4; ++am)
            af[am] = *(const short8*)(&aLds[(am * 16 + c) * LROW + q * 8]);
#pragma unroll
        for (int an = 0; an < 4; ++an)
            bfr[an] = *(const short8*)(&bLds[(wave * 64 + an * 16 + c) * LROW + q * 8]);
#pragma unroll
        for (int am = 0; am < 4; ++am)
#pragma unroll
            for (int an = 0; an < 4; ++an)
                acc[am][an] = __builtin_amdgcn_mfma_f32_16x16x32_bf16(
                    af[am], bfr[an], acc[am][an], 0, 0, 0);
    }

    // ---- epilogue: tanh, v-dot, reduce over h ----
    float vv[4];
#pragma unroll
    for (int an = 0; an < 4; ++an) vv[an] = v[wave * 64 + an * 16 + c];

#pragma unroll
    for (int am = 0; am < 4; ++am) {
#pragma unroll
        for (int r = 0; r < 4; ++r) {
            int row = am * 16 + q * 4 + r;
            long gr = rowBase + row;
            int bb  = (int)(gr & (BATCH - 1));
            const float* phrow = ph + bb * HIDDEN + wave * 64 + c;
            float s = 0.f;
#pragma unroll
            for (int an = 0; an < 4; ++an) {
                float e = acc[am][an][r] + phrow[an * 16];
                s += vv[an] * tanhf(e);
            }
            s += __shfl_xor(s, 1);
            s += __shfl_xor(s, 2);
            s += __shfl_xor(s, 4);
            s += __shfl_xor(s, 8);
            if (c == 0) atomicAdd(&sScore[row], s);
        }
    }
    __syncthreads();
    if (tid < MT) scores[rowBase + tid] = sScore[tid];
}

// ---------------- softmax over L per batch row -----------------------------
__global__ __launch_bounds__(256) void k_softmax(const float* __restrict__ scores,
                                                 float* __restrict__ out) {
    __shared__ float red[4];
    int b = blockIdx.x;
    int tid = threadIdx.x;
    float vals[4];
#pragma unroll
    for (int i = 0; i < 4; ++i)
        vals[i] = scores[(long)(tid + i * 256) * BATCH + b];

    float m = fmaxf(fmaxf(vals[0], vals[1]), fmaxf(vals[2], vals[3]));
    for (int off = 1; off < 64; off <<= 1) m = fmaxf(m, __shfl_xor(m, off));
    int wv = tid >> 6;
    if ((tid & 63) == 0) red[wv] = m;
    __syncthreads();
    m = fmaxf(fmaxf(red[0], red[1]), fmaxf(red[2], red[3]));
    __syncthreads();

    float sum = 0.f;
#pragma unroll
    for (int i = 0; i < 4; ++i) { vals[i] = __expf(vals[i] - m); sum += vals[i]; }
    for (int off = 1; off < 64; off <<= 1) sum += __shfl_xor(sum, off);
    if ((tid & 63) == 0) red[wv] = sum;
    __syncthreads();
    sum = red[0] + red[1] + red[2] + red[3];
    float inv = 1.f / sum;
#pragma unroll
    for (int i = 0; i < 4; ++i)
        out[(long)b * LSEQ + tid + i * 256] = vals[i] * inv;
}

extern "C" void kernel_launch(void* const* d_in, const int* in_sizes, int n_in,
                              void* d_out, int out_size, void* d_ws, size_t ws_size,
                              hipStream_t stream) {
    const float* hidden = (const float*)d_in[0];   // [128][512]
    const float* enc    = (const float*)d_in[1];   // [1024][128][576]
    const float* W      = (const float*)d_in[2];   // [512][1088]
    const float* bias   = (const float*)d_in[3];   // [512]
    const float* v      = (const float*)d_in[4];   // [512]
    float* out = (float*)d_out;                    // [128][1][1024]

    char* ws = (char*)d_ws;
    float* ph            = (float*)ws;                              // 256 KB
    unsigned short* WeB  = (unsigned short*)(ws + 262144);          // 576 KB
    float* scores        = (float*)(ws + 262144 + 589824);          // 512 KB

    hipLaunchKernelGGL(k_parth,   dim3(256),  dim3(256), 0, stream, hidden, W, bias, ph);
    hipLaunchKernelGGL(k_convW,   dim3(1152), dim3(256), 0, stream, W, WeB);
    hipLaunchKernelGGL(k_main,    dim3(2048), dim3(512), 0, stream, enc, WeB, ph, v, scores);
    hipLaunchKernelGGL(k_softmax, dim3(128),  dim3(256), 0, stream, scores, out);
}

// Round 2
// 726.594 us; speedup vs baseline: 1.0681x; 1.0681x over previous
//
#include <hip/hip_runtime.h>
#include <stdint.h>

#define HIDDEN 512
#define ONEHOT 64
#define EDIM   576   // HIDDEN + ONEHOT
#define BATCH  128
#define LSEQ   1024
#define FANIN  1088  // 2*HIDDEN + ONEHOT

typedef __attribute__((ext_vector_type(8))) short short8;
typedef __attribute__((ext_vector_type(4))) float f32x4;

__device__ inline unsigned short f2bf(float x) {
    union { float f; unsigned int u; } v; v.f = x;
    unsigned int u = v.u;
    unsigned int r = (u + 0x7FFFu + ((u >> 16) & 1u)) >> 16;  // RNE
    return (unsigned short)r;
}

// tanh without libcall: saturates correctly for large |x| (exp -> inf -> t -> 1)
__device__ inline float fast_tanh(float x) {
    float ax = fabsf(x);
    float e  = __expf(2.f * ax);
    float t  = 1.f - __fdividef(2.f, e + 1.f);
    return copysignf(t, x);
}

// ---------------- part_h[b][h] = hidden[b,:] . W[h,0:512] + bias[h] -------
__global__ __launch_bounds__(256) void k_parth(const float* __restrict__ hidden,
                                               const float* __restrict__ W,
                                               const float* __restrict__ bias,
                                               float* __restrict__ ph) {
    int gid = blockIdx.x * blockDim.x + threadIdx.x;   // 65536 threads
    int b = gid & (BATCH - 1);
    int h = gid >> 7;                                  // wave-uniform h
    const float* hrow = hidden + b * HIDDEN;
    const float* wrow = W + h * FANIN;
    float acc = 0.f;
#pragma unroll 4
    for (int d = 0; d < HIDDEN; d += 4) {
        float4 hv = *(const float4*)(hrow + d);
        float4 wv = *(const float4*)(wrow + d);
        acc += hv.x * wv.x + hv.y * wv.y + hv.z * wv.z + hv.w * wv.w;
    }
    ph[b * HIDDEN + h] = acc + bias[h];
}

// ---------------- We (fp32, W[:,512:]) -> bf16 chunked [9][512][64] --------
__global__ __launch_bounds__(256) void k_convW(const float* __restrict__ W,
                                               unsigned short* __restrict__ WeB) {
    int i = blockIdx.x * blockDim.x + threadIdx.x;     // 294912 elems
    int kk = i & 63;
    int h  = (i >> 6) & 511;
    int kc = i >> 15;                                  // 0..8
    WeB[i] = f2bf(W[h * FANIN + HIDDEN + kc * 64 + kk]);
}

// ---------------- main fused GEMM + tanh + v-dot ---------------------------
// Block: 256 thr (4 waves, 2x2), tile M=128 (the 128 b's of one l) x N=128 h.
// Grid: (1024 l-tiles, 4 h-tiles). K = 576 in 9 chunks of 64.
#define BK   64
#define LROW 72    // ushorts per LDS row = 144 B (16B-aligned, bank stride 4 mod 32 -> 2-way only)

__global__ __launch_bounds__(256) void k_main(
        const float* __restrict__ enc,            // [L][B][EDIM] fp32
        const unsigned short* __restrict__ WeB,   // [9][512][64] bf16
        const float* __restrict__ ph,             // [B][HIDDEN] (bias included)
        const float* __restrict__ v,
        float* __restrict__ scoresT)              // [B][L], pre-zeroed
{
    __shared__ unsigned short aLds[128 * LROW];   // 18432 B
    __shared__ unsigned short bLds[128 * LROW];   // 18432 B

    const int tid  = threadIdx.x;
    const int wave = tid >> 6;
    const int lane = tid & 63;
    const int c  = lane & 15;     // n (or m) index within 16
    const int q  = lane >> 4;     // k-octet / C row-group
    const int wm = wave & 1;      // wave row quadrant
    const int wn = wave >> 1;     // wave col quadrant
    const int l     = blockIdx.x;       // one sequence position per block
    const int hbase = blockIdx.y * 128; // h-tile

    f32x4 acc[4][4];
#pragma unroll
    for (int i = 0; i < 4; ++i)
#pragma unroll
        for (int j = 0; j < 4; ++j) acc[i][j] = (f32x4){0.f, 0.f, 0.f, 0.f};

    const float* abase = enc + (long)l * BATCH * EDIM;

    for (int kc = 0; kc < 9; ++kc) {
        // ---- global loads first (fly across the barrier wait) ----
        float4 av[8];
#pragma unroll
        for (int p = 0; p < 8; ++p) {
            int idx  = p * 256 + tid;          // 0..2047 over the 128x64 A tile
            int row  = idx >> 4;               // b
            int col4 = idx & 15;               // float4 within row
            av[p] = *(const float4*)(abase + row * EDIM + kc * BK + col4 * 4);
        }
        uint4 bv[4];
        const uint4* bs = (const uint4*)(WeB + (size_t)kc * (512 * 64) + (size_t)hbase * 64);
#pragma unroll
        for (int p = 0; p < 4; ++p) bv[p] = bs[p * 256 + tid];

        __syncthreads();   // previous iteration's LDS reads complete

        // ---- A: fp32 -> bf16 -> LDS ----
#pragma unroll
        for (int p = 0; p < 8; ++p) {
            int idx  = p * 256 + tid;
            int row  = idx >> 4;
            int col4 = idx & 15;
            ushort4 w;
            w.x = f2bf(av[p].x); w.y = f2bf(av[p].y);
            w.z = f2bf(av[p].z); w.w = f2bf(av[p].w);
            *(ushort4*)(&aLds[row * LROW + col4 * 4]) = w;
        }
        // ---- B: bf16 -> LDS (dense 128B rows -> padded 144B rows) ----
#pragma unroll
        for (int p = 0; p < 4; ++p) {
            int o  = (p * 256 + tid) * 16;     // byte offset in dense 16KB tile
            int hh = o >> 7;                   // 128 B per h-row
            int kb = o & 127;
            *(uint4*)((char*)bLds + hh * 144 + kb) = bv[p];
        }

        __syncthreads();

        // ---- 32 MFMA per wave ----
#pragma unroll
        for (int kk = 0; kk < 2; ++kk) {
            short8 af[4], bf[4];
#pragma unroll
            for (int am = 0; am < 4; ++am)
                af[am] = *(const short8*)(&aLds[(wm * 64 + am * 16 + c) * LROW + kk * 32 + q * 8]);
#pragma unroll
            for (int an = 0; an < 4; ++an)
                bf[an] = *(const short8*)(&bLds[(wn * 64 + an * 16 + c) * LROW + kk * 32 + q * 8]);
#pragma unroll
            for (int am = 0; am < 4; ++am)
#pragma unroll
                for (int an = 0; an < 4; ++an)
                    acc[am][an] = __builtin_amdgcn_mfma_f32_16x16x32_bf16(
                        af[am], bf[an], acc[am][an], 0, 0, 0);
        }
    }

    // ---- epilogue: tanh, v-dot, reduce over the 16 c-lanes, atomic combine -
    float vv[4];
#pragma unroll
    for (int an = 0; an < 4; ++an) vv[an] = v[hbase + wn * 64 + an * 16 + c];

#pragma unroll
    for (int am = 0; am < 4; ++am) {
#pragma unroll
        for (int r = 0; r < 4; ++r) {
            int b = wm * 64 + am * 16 + q * 4 + r;   // row within tile == batch idx
            const float* phr = ph + b * HIDDEN + hbase + wn * 64 + c;
            float s = 0.f;
#pragma unroll
            for (int an = 0; an < 4; ++an) {
                float e = acc[am][an][r] + phr[an * 16];
                s += vv[an] * fast_tanh(e);
            }
            s += __shfl_xor(s, 1);
            s += __shfl_xor(s, 2);
            s += __shfl_xor(s, 4);
            s += __shfl_xor(s, 8);
            if (c == 0) atomicAdd(&scoresT[(long)b * LSEQ + l], s);
        }
    }
}

// ---------------- softmax over L per batch row (coalesced [b][l]) ----------
__global__ __launch_bounds__(256) void k_softmax(const float* __restrict__ scoresT,
                                                 float* __restrict__ out) {
    __shared__ float red[4];
    int b = blockIdx.x;
    int tid = threadIdx.x;
    float vals[4];
#pragma unroll
    for (int i = 0; i < 4; ++i)
        vals[i] = scoresT[(long)b * LSEQ + tid + i * 256];

    float m = fmaxf(fmaxf(vals[0], vals[1]), fmaxf(vals[2], vals[3]));
    for (int off = 1; off < 64; off <<= 1) m = fmaxf(m, __shfl_xor(m, off));
    int wv = tid >> 6;
    if ((tid & 63) == 0) red[wv] = m;
    __syncthreads();
    m = fmaxf(fmaxf(red[0], red[1]), fmaxf(red[2], red[3]));
    __syncthreads();

    float sum = 0.f;
#pragma unroll
    for (int i = 0; i < 4; ++i) { vals[i] = __expf(vals[i] - m); sum += vals[i]; }
    for (int off = 1; off < 64; off <<= 1) sum += __shfl_xor(sum, off);
    if ((tid & 63) == 0) red[wv] = sum;
    __syncthreads();
    sum = red[0] + red[1] + red[2] + red[3];
    float inv = 1.f / sum;
#pragma unroll
    for (int i = 0; i < 4; ++i)
        out[(long)b * LSEQ + tid + i * 256] = vals[i] * inv;
}

extern "C" void kernel_launch(void* const* d_in, const int* in_sizes, int n_in,
                              void* d_out, int out_size, void* d_ws, size_t ws_size,
                              hipStream_t stream) {
    const float* hidden = (const float*)d_in[0];   // [128][512]
    const float* enc    = (const float*)d_in[1];   // [1024][128][576]
    const float* W      = (const float*)d_in[2];   // [512][1088]
    const float* bias   = (const float*)d_in[3];   // [512]
    const float* v      = (const float*)d_in[4];   // [512]
    float* out = (float*)d_out;                    // [128][1][1024]

    char* ws = (char*)d_ws;
    float* ph            = (float*)ws;                              // 256 KB
    unsigned short* WeB  = (unsigned short*)(ws + 262144);          // 576 KB
    float* scoresT       = (float*)(ws + 262144 + 589824);          // 512 KB

    hipLaunchKernelGGL(k_parth, dim3(256),  dim3(256), 0, stream, hidden, W, bias, ph);
    hipLaunchKernelGGL(k_convW, dim3(1152), dim3(256), 0, stream, W, WeB);
    hipMemsetAsync(scoresT, 0, BATCH * LSEQ * sizeof(float), stream);
    hipLaunchKernelGGL(k_main, dim3(1024, 4), dim3(256), 0, stream, enc, WeB, ph, v, scoresT);
    hipLaunchKernelGGL(k_softmax, dim3(128), dim3(256), 0, stream, scoresT, out);
}

// Round 3
// 526.035 us; speedup vs baseline: 1.4754x; 1.3813x over previous
//
#include <hip/hip_runtime.h>
#include <stdint.h>

#define HIDDEN 512
#define ONEHOT 64
#define EDIM   576   // HIDDEN + ONEHOT
#define BATCH  128
#define LSEQ   1024
#define FANIN  1088  // 2*HIDDEN + ONEHOT

typedef __attribute__((ext_vector_type(8))) short short8;
typedef __attribute__((ext_vector_type(4))) float f32x4;

__device__ inline unsigned short f2bf(float x) {
    union { float f; unsigned int u; } v; v.f = x;
    unsigned int u = v.u;
    unsigned int r = (u + 0x7FFFu + ((u >> 16) & 1u)) >> 16;  // RNE
    return (unsigned short)r;
}

__device__ inline float fast_tanh(float x) {
    float ax = fabsf(x);
    float e  = __expf(2.f * ax);
    float t  = 1.f - __fdividef(2.f, e + 1.f);
    return copysignf(t, x);
}

// ---- prep: part_h[b][h] = hidden.W[:, :512]^T + bias  AND  We -> bf16 -----
// WeB layout: [kc 9][h 512][g' 8][j 8], where the element stored at group g'
// is logical k = (g' ^ (h&7))*8 + j  -- an XOR swizzle so the LDS image
// (loaded via global_load_lds, lane*16B order) has conflict-free frag reads.
__global__ __launch_bounds__(256) void k_prep(const float* __restrict__ hidden,
                                              const float* __restrict__ W,
                                              const float* __restrict__ bias,
                                              float* __restrict__ ph,
                                              unsigned short* __restrict__ WeB) {
    int bid = blockIdx.x;
    int tid = threadIdx.x;
    if (bid < 256) {
        int gid = bid * 256 + tid;                 // 65536 threads
        int b = gid & (BATCH - 1);
        int h = gid >> 7;
        const float* hrow = hidden + b * HIDDEN;
        const float* wrow = W + h * FANIN;
        float acc = 0.f;
#pragma unroll 4
        for (int d = 0; d < HIDDEN; d += 4) {
            float4 hv = *(const float4*)(hrow + d);
            float4 wv = *(const float4*)(wrow + d);
            acc += hv.x * wv.x + hv.y * wv.y + hv.z * wv.z + hv.w * wv.w;
        }
        ph[b * HIDDEN + h] = acc + bias[h];
    } else {
        int i = (bid - 256) * 256 + tid;           // 0..294911
        int kc = i >> 15;                          // 0..8
        int h  = (i >> 6) & 511;
        int g  = (i >> 3) & 7;                     // physical 16B group
        int j  = i & 7;
        int k  = ((g ^ (h & 7)) << 3) | j;         // logical k in chunk
        WeB[i] = f2bf(W[h * FANIN + HIDDEN + kc * 64 + k]);
    }
}

// ---- main fused GEMM + tanh + v-dot ---------------------------------------
// 512 thr = 8 waves (4 vm x 2 vn), wave tile 32m x 64n. Block tile: M=128
// (all b of one l) x N=128 h. Grid (4 h-tiles fast, 1024 l) so the 4 blocks
// sharing an enc A-tile dispatch together (L2/L3 reuse).
#define AROW 72   // ushorts per A-LDS row = 144 B (16B-aligned, conflict-free)

__global__ __launch_bounds__(512) void k_main(
        const float* __restrict__ enc,            // [L][B][EDIM] fp32
        const unsigned short* __restrict__ WeB,   // swizzled [9][512][64] bf16
        const float* __restrict__ ph,             // [B][HIDDEN] (bias included)
        const float* __restrict__ v,
        float* __restrict__ scoresP)              // [8 slots][L][B] partials
{
    __shared__ unsigned short aLds[128 * AROW];   // 18432 B
    __shared__ unsigned short bLds[128 * 64];     // 16384 B (dense: DMA target)

    const int tid  = threadIdx.x;
    const int wave = tid >> 6;
    const int lane = tid & 63;
    const int c  = lane & 15;
    const int q  = lane >> 4;
    const int vm = wave & 3;      // m quadrant (32 rows)
    const int vn = wave >> 2;     // n half (64 cols)
    const int ht = blockIdx.x;    // h-tile 0..3
    const int l  = blockIdx.y;
    const int hbase = ht * 128;

    f32x4 acc[2][4];
#pragma unroll
    for (int i = 0; i < 2; ++i)
#pragma unroll
        for (int j = 0; j < 4; ++j) acc[i][j] = (f32x4){0.f, 0.f, 0.f, 0.f};

    const float* abase = enc + (size_t)l * (BATCH * EDIM);
    const char*  bsrc  = (const char*)WeB + (size_t)ht * 16384;

    for (int kc = 0; kc < 9; ++kc) {
        // A global loads (fp32) -- issue before barrier, fly across the wait
        float4 av[4];
#pragma unroll
        for (int p = 0; p < 4; ++p) {
            int idx = p * 512 + tid;               // 2048 float4 = 128x64 tile
            int row = idx >> 4;
            int c4  = idx & 15;
            av[p] = *(const float4*)(abase + row * EDIM + kc * 64 + c4 * 4);
        }

        __syncthreads();   // previous iteration's LDS reads complete

        // B tile: async DMA global->LDS, 16 B/lane, dense image
#pragma unroll
        for (int p = 0; p < 2; ++p) {
            int off = p * 8192 + wave * 1024;
            __builtin_amdgcn_global_load_lds(
                (const __attribute__((address_space(1))) unsigned int*)
                    (bsrc + (size_t)kc * 65536 + off + lane * 16),
                (__attribute__((address_space(3))) unsigned int*)
                    ((char*)bLds + off),
                16, 0, 0);
        }

        // A: fp32 -> bf16 -> LDS (padded 144 B rows)
#pragma unroll
        for (int p = 0; p < 4; ++p) {
            int idx = p * 512 + tid;
            int row = idx >> 4;
            int c4  = idx & 15;
            ushort4 w;
            w.x = f2bf(av[p].x); w.y = f2bf(av[p].y);
            w.z = f2bf(av[p].z); w.w = f2bf(av[p].w);
            *(ushort4*)(&aLds[row * AROW + c4 * 4]) = w;
        }

        __syncthreads();   // waits vmcnt(0) (B DMA) + lgkm (A writes)

#pragma unroll
        for (int kk = 0; kk < 2; ++kk) {
            short8 af[2], bf[4];
#pragma unroll
            for (int am = 0; am < 2; ++am)
                af[am] = *(const short8*)(&aLds[(vm * 32 + am * 16 + c) * AROW + kk * 32 + q * 8]);
#pragma unroll
            for (int an = 0; an < 4; ++an) {
                int row = vn * 64 + an * 16 + c;
                int g   = ((kk << 2) | q) ^ (c & 7);     // undo swizzle
                bf[an]  = *(const short8*)((const char*)bLds + row * 128 + g * 16);
            }
#pragma unroll
            for (int am = 0; am < 2; ++am)
#pragma unroll
                for (int an = 0; an < 4; ++an)
                    acc[am][an] = __builtin_amdgcn_mfma_f32_16x16x32_bf16(
                        af[am], bf[an], acc[am][an], 0, 0, 0);
        }
    }

    // ---- epilogue: tanh, v-dot, reduce over 16 c-lanes, slot store --------
    float vv[4];
#pragma unroll
    for (int an = 0; an < 4; ++an) vv[an] = v[hbase + vn * 64 + an * 16 + c];

    const int slot = ht * 2 + vn;
#pragma unroll
    for (int am = 0; am < 2; ++am) {
#pragma unroll
        for (int r = 0; r < 4; ++r) {
            int b = vm * 32 + am * 16 + q * 4 + r;
            const float* phr = ph + b * HIDDEN + hbase + vn * 64 + c;
            float s = 0.f;
#pragma unroll
            for (int an = 0; an < 4; ++an) {
                float e = acc[am][an][r] + phr[an * 16];
                s += vv[an] * fast_tanh(e);
            }
            s += __shfl_xor(s, 1);
            s += __shfl_xor(s, 2);
            s += __shfl_xor(s, 4);
            s += __shfl_xor(s, 8);
            if (c == 0)
                scoresP[((size_t)slot * LSEQ + l) * BATCH + b] = s;
        }
    }
}

// ---- softmax over L per batch row; sums the 8 partial slots ---------------
__global__ __launch_bounds__(256) void k_softmax(const float* __restrict__ sp,
                                                 float* __restrict__ out) {
    __shared__ float red[4];
    int b = blockIdx.x;
    int tid = threadIdx.x;
    float vals[4];
#pragma unroll
    for (int i = 0; i < 4; ++i) {
        int li = tid + i * 256;
        float s = 0.f;
#pragma unroll
        for (int sl = 0; sl < 8; ++sl)
            s += sp[((size_t)sl * LSEQ + li) * BATCH + b];
        vals[i] = s;
    }

    float m = fmaxf(fmaxf(vals[0], vals[1]), fmaxf(vals[2], vals[3]));
    for (int off = 1; off < 64; off <<= 1) m = fmaxf(m, __shfl_xor(m, off));
    int wv = tid >> 6;
    if ((tid & 63) == 0) red[wv] = m;
    __syncthreads();
    m = fmaxf(fmaxf(red[0], red[1]), fmaxf(red[2], red[3]));
    __syncthreads();

    float sum = 0.f;
#pragma unroll
    for (int i = 0; i < 4; ++i) { vals[i] = __expf(vals[i] - m); sum += vals[i]; }
    for (int off = 1; off < 64; off <<= 1) sum += __shfl_xor(sum, off);
    if ((tid & 63) == 0) red[wv] = sum;
    __syncthreads();
    sum = red[0] + red[1] + red[2] + red[3];
    float inv = 1.f / sum;
#pragma unroll
    for (int i = 0; i < 4; ++i)
        out[(size_t)b * LSEQ + tid + i * 256] = vals[i] * inv;
}

extern "C" void kernel_launch(void* const* d_in, const int* in_sizes, int n_in,
                              void* d_out, int out_size, void* d_ws, size_t ws_size,
                              hipStream_t stream) {
    const float* hidden = (const float*)d_in[0];   // [128][512]
    const float* enc    = (const float*)d_in[1];   // [1024][128][576]
    const float* W      = (const float*)d_in[2];   // [512][1088]
    const float* bias   = (const float*)d_in[3];   // [512]
    const float* v      = (const float*)d_in[4];   // [512]
    float* out = (float*)d_out;                    // [128][1][1024]

    char* ws = (char*)d_ws;
    float* ph           = (float*)ws;                       // 256 KB
    unsigned short* WeB = (unsigned short*)(ws + 262144);   // 576 KB
    float* scoresP      = (float*)(ws + 851968);            // 4 MB [8][L][B]

    hipLaunchKernelGGL(k_prep, dim3(1408), dim3(256), 0, stream,
                       hidden, W, bias, ph, WeB);
    hipLaunchKernelGGL(k_main, dim3(4, 1024), dim3(512), 0, stream,
                       enc, WeB, ph, v, scoresP);
    hipLaunchKernelGGL(k_softmax, dim3(128), dim3(256), 0, stream, scoresP, out);
}